// Round 4
// baseline (32.879 us; speedup 1.0000x reference)
//
#include <hip/hip_runtime.h>
#include <hip/hip_fp16.h>

#define BATCH 2
#define CCH   256
#define WDIM  64
#define HW    4096   // 64*64
#define KWIN  49

__device__ __forceinline__ __half2 u2h2(unsigned u) {
    union { unsigned u; __half2 h; } v; v.u = u; return v.h;
}
__device__ __forceinline__ unsigned h22u(__half2 h) {
    union { unsigned u; __half2 h; } v; v.h = h; return v.u;
}

// ---------------------------------------------------------------------------
// Kernel 1: bilinear warp of f2 by c1 (zero padding) + transpose into
// channel-last f16 [B, HW, C], plus the c1 passthrough copy (output 0).
// f1 is NOT touched here anymore (corr loads it directly).
// grid = (B * HW/64, C/64) = (128, 4), block = 256.
// LDS 64x65 padded fp32 tile: phase-A lane=pixel (stride-65, conflict-free),
// phase-B 4ch/lane reads are 2-way aliased (free), uint2 f16 stores.
// ---------------------------------------------------------------------------
__global__ __launch_bounds__(256) void warp_kernel(
    const float* __restrict__ f2, const float* __restrict__ c1,
    __half* __restrict__ f2wt, float* __restrict__ out0)
{
    __shared__ float s2[64][65];

    const int t  = threadIdx.x;
    const int b  = blockIdx.x >> 6;          // 64 blocks per batch
    const int nb = (blockIdx.x & 63) << 6;   // pixel base
    const int cc = blockIdx.y << 6;          // channel base

    // output 0: c1 passthrough (16384 floats over the 128 x-blocks)
    if (cc == 0 && t < 128) {
        const int idx = blockIdx.x * 128 + t;
        out0[idx] = c1[idx];
    }

    const int pix = t & 63;                  // lane = pixel (coalesced n)
    const int tq  = t >> 6;                  // wave id 0..3
    const int n   = nb + pix;

    const float cx = c1[(b * 2 + 0) * HW + n];
    const float cy = c1[(b * 2 + 1) * HW + n];
    const float x0f = floorf(cx), y0f = floorf(cy);
    const float fx = cx - x0f, fy = cy - y0f;
    const int ix0 = (int)x0f, iy0 = (int)y0f;
    const int ix1 = ix0 + 1,  iy1 = iy0 + 1;

    float w00 = (1.f - fx) * (1.f - fy);
    float w01 = fx * (1.f - fy);
    float w10 = (1.f - fx) * fy;
    float w11 = fx * fy;
    if (ix0 < 0 || ix0 >= WDIM) { w00 = 0.f; w10 = 0.f; }
    if (ix1 < 0 || ix1 >= WDIM) { w01 = 0.f; w11 = 0.f; }
    if (iy0 < 0 || iy0 >= WDIM) { w00 = 0.f; w01 = 0.f; }
    if (iy1 < 0 || iy1 >= WDIM) { w10 = 0.f; w11 = 0.f; }
    const int xc0 = min(max(ix0, 0), WDIM - 1);
    const int xc1 = min(max(ix1, 0), WDIM - 1);
    const int yc0 = min(max(iy0, 0), WDIM - 1);
    const int yc1 = min(max(iy1, 0), WDIM - 1);
    const int o00 = yc0 * WDIM + xc0, o01 = yc0 * WDIM + xc1;
    const int o10 = yc1 * WDIM + xc0, o11 = yc1 * WDIM + xc1;

    const float* f2b = f2 + ((size_t)b * CCH + cc) * HW;

    #pragma unroll
    for (int j = 0; j < 16; ++j) {
        const int cl = tq * 16 + j;              // local channel 0..63
        const float* p2 = f2b + (size_t)cl * HW;
        s2[cl][pix] = w00 * p2[o00] + w01 * p2[o01] +
                      w10 * p2[o10] + w11 * p2[o11];
    }
    __syncthreads();

    // phase B: lane packs 4 consecutive channels of one pixel -> uint2 store
    const int lo = t & 15;                       // channel quad: 4*lo..+3
    const int pq = t >> 4;                       // 0..15
    ushort* o2 = (ushort*)f2wt;
    #pragma unroll
    for (int j = 0; j < 4; ++j) {
        const int pix2 = j * 16 + pq;
        const int c4 = 4 * lo;
        const size_t base = ((size_t)(b * HW + nb + pix2)) * CCH + cc + c4;
        uint2 vb;
        vb.x = h22u(__float22half2_rn(make_float2(s2[c4 + 0][pix2],
                                                  s2[c4 + 1][pix2])));
        vb.y = h22u(__float22half2_rn(make_float2(s2[c4 + 2][pix2],
                                                  s2[c4 + 3][pix2])));
        *(uint2*)(o2 + base) = vb;
    }
}

// ---------------------------------------------------------------------------
// Kernel 2: correlation. Block = 4 consecutive pixels (1 wave each).
// Cooperative f1 load: thread = channel, float4 = the block's 4 pixels;
// f16-convert into a 2KB LDS transpose (s_q). Then per wave: lane split
// g = window column, j = channel chunk; per window row 4 uint4 gathers
// (8 lines/instr) + 16 v_pk_fma_f16; 3 shfl_xor group reduce; per-wave LDS
// redistribute; 49 bilinear-combined outputs.
// grid = B*HW/4 = 2048 blocks (XCD-swizzled), block = 256.
// ---------------------------------------------------------------------------
__global__ __launch_bounds__(256) void corr_kernel(
    const float* __restrict__ f1,
    const __half* __restrict__ f2wt,
    const float* __restrict__ c0, float* __restrict__ outc)
{
    __shared__ __half s_q[4][256];
    __shared__ float  sD[4][64];

    const int t    = threadIdx.x;
    const int lane = t & 63;
    const int wv   = t >> 6;
    const int j    = lane & 7;    // channel chunk
    const int g    = lane >> 3;   // window column ix

    // XCD-aware bijective swizzle: 2048 = 8 * 256
    const int bid = blockIdx.x;
    const int swz = (bid & 7) * 256 + (bid >> 3);
    const int n0g = swz * 4;                 // block's first global pixel
    const int b   = n0g >> 12;
    const int n0  = n0g & 4095;

    // cooperative f1 load + f16 transpose: thread = channel, 4 pixels
    {
        const float4 v = *(const float4*)(f1 + ((size_t)(b * CCH + t)) * HW + n0);
        s_q[0][t] = __float2half(v.x);
        s_q[1][t] = __float2half(v.y);
        s_q[2][t] = __float2half(v.z);
        s_q[3][t] = __float2half(v.w);
    }
    __syncthreads();

    const int n = n0 + wv;
    const float cx = c0[(b * 2 + 0) * HW + n];
    const float cy = c0[(b * 2 + 1) * HW + n];
    const float x0f = floorf(cx), y0f = floorf(cy);
    const float fx = cx - x0f, fy = cy - y0f;
    const int bx = (int)x0f - 3, by = (int)y0f - 3;

    // q: this lane's 32 channels (i*64 + j*8 .. +7) from LDS, packed half2
    const ushort* qrow = (const ushort*)&s_q[wv][0];
    __half2 qh[16];
    #pragma unroll
    for (int i = 0; i < 4; ++i) {
        uint4 u = *(const uint4*)(qrow + i * 64 + j * 8);
        qh[i * 4 + 0] = u2h2(u.x);
        qh[i * 4 + 1] = u2h2(u.y);
        qh[i * 4 + 2] = u2h2(u.z);
        qh[i * 4 + 3] = u2h2(u.w);
    }

    const int px = bx + g;
    const bool pxok = (px >= 0) && (px < WDIM);
    const ushort* wbase = (const ushort*)f2wt + ((size_t)b * HW) * CCH;

    #pragma unroll
    for (int o = 0; o < 8; ++o) {
        const int py = by + o;
        float a = 0.f;
        if (pxok && py >= 0 && py < WDIM) {
            const ushort* wrow = wbase + ((size_t)(py * WDIM + px)) * CCH;
            __half2 acc0 = __halves2half2(__float2half(0.f), __float2half(0.f));
            __half2 acc1 = acc0;
            #pragma unroll
            for (int i = 0; i < 4; ++i) {
                uint4 u = *(const uint4*)(wrow + i * 64 + j * 8);
                acc0 = __hfma2(qh[i * 4 + 0], u2h2(u.x), acc0);
                acc1 = __hfma2(qh[i * 4 + 1], u2h2(u.y), acc1);
                acc0 = __hfma2(qh[i * 4 + 2], u2h2(u.z), acc0);
                acc1 = __hfma2(qh[i * 4 + 3], u2h2(u.w), acc1);
            }
            const __half2 s = __hadd2(acc0, acc1);
            a = __low2float(s) + __high2float(s);
        }
        a += __shfl_xor(a, 1, 64);
        a += __shfl_xor(a, 2, 64);
        a += __shfl_xor(a, 4, 64);
        if (j == 0) sD[wv][o * 8 + g] = a;   // D[iy=o][ix=g]
    }
    // sD[wv] written and read by the same wave: program-order DS, no barrier

    const int k = lane;
    if (k < KWIN) {
        const int dyi = k / 7;
        const int dxi = k % 7;
        const int s   = dyi * 8 + dxi;
        const float d00 = sD[wv][s];
        const float d01 = sD[wv][s + 1];
        const float d10 = sD[wv][s + 8];
        const float d11 = sD[wv][s + 9];
        const float w00 = (1.f - fx) * (1.f - fy);
        const float w01 = fx * (1.f - fy);
        const float w10 = (1.f - fx) * fy;
        const float w11 = fx * fy;
        const float r = (w00 * d00 + w01 * d01 + w10 * d10 + w11 * d11) * 0.0625f;
        outc[(size_t)(b * KWIN + k) * HW + n] = r;
    }
}

extern "C" void kernel_launch(void* const* d_in, const int* in_sizes, int n_in,
                              void* d_out, int out_size, void* d_ws, size_t ws_size,
                              hipStream_t stream) {
    (void)in_sizes; (void)n_in; (void)out_size; (void)ws_size;
    const float* f1 = (const float*)d_in[0];
    const float* f2 = (const float*)d_in[1];
    const float* c1 = (const float*)d_in[2];
    const float* c0 = (const float*)d_in[3];
    float* out = (float*)d_out;

    __half* f2wt = (__half*)d_ws;    // [B,HW,C] f16, 4 MB

    dim3 g1(BATCH * (HW / 64), CCH / 64);
    warp_kernel<<<g1, 256, 0, stream>>>(f2, c1, f2wt, out);

    corr_kernel<<<(BATCH * HW) / 4, 256, 0, stream>>>(f1, f2wt, c0, out + BATCH * 2 * HW);
}

// Round 5
// 26.989 us; speedup vs baseline: 1.2182x; 1.2182x over previous
//
#include <hip/hip_runtime.h>
#include <hip/hip_fp16.h>

#define BATCH 2
#define CCH   256
#define WDIM  64
#define HW    4096   // 64*64
#define KWIN  49

// corr tile geometry: 8 wide (x) x 4 tall (y) = 32 pixels per block
#define UW    15     // union window cols  (8 px x-span + 7)
#define UH    11     // union window rows  (4 px y-span + 7)
#define UPOS  165    // UW*UH
#define NT    11     // n-tiles of 16 (176 >= 165)
#define DSTR  177    // D row stride (odd -> bank spread)

using f16x8 = __attribute__((ext_vector_type(8))) _Float16;
using f32x4 = __attribute__((ext_vector_type(4))) float;

__device__ __forceinline__ __half2 u2h2(unsigned u) {
    union { unsigned u; __half2 h; } v; v.u = u; return v.h;
}
__device__ __forceinline__ unsigned h22u(__half2 h) {
    union { unsigned u; __half2 h; } v; v.h = h; return v.u;
}
__device__ __forceinline__ f16x8 ldfrag(const ushort* p) {
    return __builtin_bit_cast(f16x8, *(const uint4*)p);
}

// ---------------------------------------------------------------------------
// Kernel 1 (validated R3 version): bilinear warp of f2 by c1 (zero padding)
// fused with transpose of f2w AND f1 into channel-last f16 [B, HW, C],
// plus the c1 passthrough copy (output 0).
// grid = (128, 4), block = 256. LDS 64x65 padded fp32 tiles.
// ---------------------------------------------------------------------------
__global__ __launch_bounds__(256) void warp_transpose_kernel(
    const float* __restrict__ f1, const float* __restrict__ f2,
    const float* __restrict__ c1, __half* __restrict__ f1t,
    __half* __restrict__ f2wt, float* __restrict__ out0)
{
    __shared__ float s1[64][65];
    __shared__ float s2[64][65];

    const int t  = threadIdx.x;
    const int b  = blockIdx.x >> 6;
    const int nb = (blockIdx.x & 63) << 6;
    const int cc = blockIdx.y << 6;

    if (cc == 0 && t < 128) {
        const int idx = blockIdx.x * 128 + t;
        out0[idx] = c1[idx];
    }

    const int pix = t & 63;
    const int tq  = t >> 6;
    const int n   = nb + pix;

    const float cx = c1[(b * 2 + 0) * HW + n];
    const float cy = c1[(b * 2 + 1) * HW + n];
    const float x0f = floorf(cx), y0f = floorf(cy);
    const float fx = cx - x0f, fy = cy - y0f;
    const int ix0 = (int)x0f, iy0 = (int)y0f;
    const int ix1 = ix0 + 1,  iy1 = iy0 + 1;

    float w00 = (1.f - fx) * (1.f - fy);
    float w01 = fx * (1.f - fy);
    float w10 = (1.f - fx) * fy;
    float w11 = fx * fy;
    if (ix0 < 0 || ix0 >= WDIM) { w00 = 0.f; w10 = 0.f; }
    if (ix1 < 0 || ix1 >= WDIM) { w01 = 0.f; w11 = 0.f; }
    if (iy0 < 0 || iy0 >= WDIM) { w00 = 0.f; w01 = 0.f; }
    if (iy1 < 0 || iy1 >= WDIM) { w10 = 0.f; w11 = 0.f; }
    const int xc0 = min(max(ix0, 0), WDIM - 1);
    const int xc1 = min(max(ix1, 0), WDIM - 1);
    const int yc0 = min(max(iy0, 0), WDIM - 1);
    const int yc1 = min(max(iy1, 0), WDIM - 1);
    const int o00 = yc0 * WDIM + xc0, o01 = yc0 * WDIM + xc1;
    const int o10 = yc1 * WDIM + xc0, o11 = yc1 * WDIM + xc1;

    const float* f2b = f2 + ((size_t)b * CCH + cc) * HW;
    const float* f1b = f1 + ((size_t)b * CCH + cc) * HW;

    #pragma unroll
    for (int j = 0; j < 16; ++j) {
        const int cl = tq * 16 + j;
        const float* p2 = f2b + (size_t)cl * HW;
        s2[cl][pix] = w00 * p2[o00] + w01 * p2[o01] +
                      w10 * p2[o10] + w11 * p2[o11];
        s1[cl][pix] = f1b[(size_t)cl * HW + n];
    }
    __syncthreads();

    const int lo = t & 15;                       // channel quad
    const int pq = t >> 4;                       // 0..15
    ushort* o1 = (ushort*)f1t;
    ushort* o2 = (ushort*)f2wt;
    #pragma unroll
    for (int j = 0; j < 4; ++j) {
        const int pix2 = j * 16 + pq;
        const int c4 = 4 * lo;
        const size_t base = ((size_t)(b * HW + nb + pix2)) * CCH + cc + c4;
        uint2 va, vb;
        va.x = h22u(__float22half2_rn(make_float2(s1[c4 + 0][pix2], s1[c4 + 1][pix2])));
        va.y = h22u(__float22half2_rn(make_float2(s1[c4 + 2][pix2], s1[c4 + 3][pix2])));
        vb.x = h22u(__float22half2_rn(make_float2(s2[c4 + 0][pix2], s2[c4 + 1][pix2])));
        vb.y = h22u(__float22half2_rn(make_float2(s2[c4 + 2][pix2], s2[c4 + 3][pix2])));
        *(uint2*)(o1 + base) = va;
        *(uint2*)(o2 + base) = vb;
    }
}

// ---------------------------------------------------------------------------
// Kernel 2: tiled MFMA correlation. Block = 4x8 pixel tile (32 px), 512 thr
// (8 waves). If the tile's floor(c0) span fits (x<=7, y<=3), all 32 windows
// lie in a 15x11 union: GEMM Q[32x256] x W^T[165x256] via
// mfma_f32_16x16x32_f16, K in two 128-ch halves (LDS < 64KB), D -> LDS,
// per-pixel bilinear combine of 4 D entries. Else: block-uniform per-pixel
// fallback (general coords). XOR chunk-swizzle (c ^= row&7) on A/B rows
// kills the 16-way fragment-read bank conflict. OOB union rows staged as 0
// (exact zero-padding semantics).
// grid = 256 blocks (XCD-swizzled: 8 x 32).
// ---------------------------------------------------------------------------
__global__ __launch_bounds__(512) void corr_mfma_kernel(
    const __half* __restrict__ f1t, const __half* __restrict__ f2wt,
    const float* __restrict__ c0, float* __restrict__ outc)
{
    // RAW: A16 [32 rows][32 chunks][16B] = 16 KB, B16 [176 rows][16 chunks][16B] = 44 KB
    __shared__ __align__(16) char RAW[16384 + 176 * 128 * 2];
    __shared__ float s_fx[32], s_fy[32];
    __shared__ int   s_lbx[32], s_lby[32], s_meta[3];

    ushort* A16 = (ushort*)RAW;
    ushort* B16 = (ushort*)(RAW + 16384);
    float*  Dex = (float*)(RAW + 16384);      // overlays B after compute

    const int t    = threadIdx.x;
    const int l    = t & 63;
    const int wv   = t >> 6;

    // XCD-aware bijective swizzle: 256 = 8 * 32 (keeps x-stripes per XCD)
    const int bid = blockIdx.x;
    const int swz = (bid & 7) * 32 + (bid >> 3);
    const int b   = swz >> 7;
    const int tau = swz & 127;
    const int ty  = tau >> 3, tx = tau & 7;
    const int n0  = ty * 256 + tx * 8;        // tile base pixel

    const ushort* f1u = (const ushort*)f1t + ((size_t)b * HW) * CCH;
    const ushort* f2u = (const ushort*)f2wt + ((size_t)b * HW) * CCH;

    // ---- meta phase (wave 0): per-pixel coords + span reduce ----
    if (wv == 0) {
        const int p = l;
        float cx = 0.f, cy = 0.f;
        int ifx = 0, ify = 0;
        if (p < 32) {
            const int n = n0 + ((p >> 3) << 6) + (p & 7);
            cx = c0[(b * 2 + 0) * HW + n];
            cy = c0[(b * 2 + 1) * HW + n];
            ifx = (int)floorf(cx);
            ify = (int)floorf(cy);
        }
        int mnx = (p < 32) ? ifx : 0x7fffffff;
        int mxx = (p < 32) ? ifx : (-0x7fffffff - 1);
        int mny = (p < 32) ? ify : 0x7fffffff;
        int mxy = (p < 32) ? ify : (-0x7fffffff - 1);
        #pragma unroll
        for (int off = 1; off < 64; off <<= 1) {
            mnx = min(mnx, __shfl_xor(mnx, off, 64));
            mxx = max(mxx, __shfl_xor(mxx, off, 64));
            mny = min(mny, __shfl_xor(mny, off, 64));
            mxy = max(mxy, __shfl_xor(mxy, off, 64));
        }
        if (p < 32) {
            s_fx[p]  = cx - floorf(cx);
            s_fy[p]  = cy - floorf(cy);
            s_lbx[p] = ifx - mnx;
            s_lby[p] = ify - mny;
        }
        if (l == 0) {
            s_meta[0] = mnx - 3;
            s_meta[1] = mny - 3;
            s_meta[2] = (mxx - mnx <= 7) && (mxy - mny <= 3);
        }
    }
    __syncthreads();

    const int bx0 = s_meta[0], by0 = s_meta[1], contained = s_meta[2];

    if (contained) {
        // ---- stage A (full 256 ch) + B half 0, XOR-swizzled ----
        for (int i = t; i < 32 * 32; i += 512) {
            const int r = i >> 5, c = i & 31;
            const int n = n0 + ((r >> 3) << 6) + (r & 7);
            const uint4 v = *(const uint4*)(f1u + (size_t)n * CCH + c * 8);
            *(uint4*)(A16 + r * 256 + ((c ^ (r & 7)) << 3)) = v;
        }
        for (int i = t; i < UPOS * 16; i += 512) {
            const int r = i >> 4, c = i & 15;
            const int wy = r / UW, wx = r - wy * UW;
            const int py = by0 + wy, px = bx0 + wx;
            uint4 v = {0u, 0u, 0u, 0u};
            if (px >= 0 && px < WDIM && py >= 0 && py < WDIM)
                v = *(const uint4*)(f2u + (size_t)(py * WDIM + px) * CCH + c * 8);
            *(uint4*)(B16 + r * 128 + ((c ^ (r & 7)) << 3)) = v;
        }
        __syncthreads();

        // ---- MFMA: wave -> (m-tile, n-group) ----
        const int mt = wv & 1;          // m-tile (16 px)
        const int ng = wv >> 1;         // n-group
        const int nnt = (ng == 3) ? 2 : 3;
        int nt[3] = {ng, ng + 4, ng + 8};
        f32x4 acc[3];
        #pragma unroll
        for (int i = 0; i < 3; ++i) acc[i] = f32x4{0.f, 0.f, 0.f, 0.f};

        const int g    = l >> 4;
        const int arow = mt * 16 + (l & 15);
        const int axr  = arow & 7;

        // half 0
        {
            f16x8 af[4];
            #pragma unroll
            for (int s = 0; s < 4; ++s)
                af[s] = ldfrag(A16 + arow * 256 + (((s * 4 + g) ^ axr) << 3));
            #pragma unroll
            for (int i = 0; i < 3; ++i) if (i < nnt) {
                const int brow = nt[i] * 16 + (l & 15);
                const int bxr  = brow & 7;
                #pragma unroll
                for (int s = 0; s < 4; ++s) {
                    const f16x8 bf = ldfrag(B16 + brow * 128 + (((s * 4 + g) ^ bxr) << 3));
                    acc[i] = __builtin_amdgcn_mfma_f32_16x16x32_f16(af[s], bf, acc[i], 0, 0, 0);
                }
            }
        }
        __syncthreads();   // all B-half-0 reads done

        // ---- stage B half 1 ----
        for (int i = t; i < UPOS * 16; i += 512) {
            const int r = i >> 4, c = i & 15;
            const int wy = r / UW, wx = r - wy * UW;
            const int py = by0 + wy, px = bx0 + wx;
            uint4 v = {0u, 0u, 0u, 0u};
            if (px >= 0 && px < WDIM && py >= 0 && py < WDIM)
                v = *(const uint4*)(f2u + (size_t)(py * WDIM + px) * CCH + 128 + c * 8);
            *(uint4*)(B16 + r * 128 + ((c ^ (r & 7)) << 3)) = v;
        }
        __syncthreads();

        // half 1
        {
            f16x8 af[4];
            #pragma unroll
            for (int s = 0; s < 4; ++s)
                af[s] = ldfrag(A16 + arow * 256 + (((16 + s * 4 + g) ^ axr) << 3));
            #pragma unroll
            for (int i = 0; i < 3; ++i) if (i < nnt) {
                const int brow = nt[i] * 16 + (l & 15);
                const int bxr  = brow & 7;
                #pragma unroll
                for (int s = 0; s < 4; ++s) {
                    const f16x8 bf = ldfrag(B16 + brow * 128 + (((s * 4 + g) ^ bxr) << 3));
                    acc[i] = __builtin_amdgcn_mfma_f32_16x16x32_f16(af[s], bf, acc[i], 0, 0, 0);
                }
            }
        }
        __syncthreads();   // A,B dead -> D may overlay

        // ---- D -> LDS ----
        #pragma unroll
        for (int i = 0; i < 3; ++i) if (i < nnt) {
            #pragma unroll
            for (int r4 = 0; r4 < 4; ++r4) {
                Dex[(mt * 16 + (l >> 4) * 4 + r4) * DSTR + nt[i] * 16 + (l & 15)] = acc[i][r4];
            }
        }
        __syncthreads();

        // ---- output: bilinear combine of 4 D entries per (pixel, k) ----
        for (int idx = t; idx < 32 * KWIN; idx += 512) {
            const int p = idx & 31, k = idx >> 5;
            const int dyi = k / 7, dxi = k - dyi * 7;
            const int pos = (s_lby[p] + dyi) * UW + s_lbx[p] + dxi;
            const float* dr = Dex + p * DSTR + pos;
            const float d00 = dr[0], d01 = dr[1], d10 = dr[UW], d11 = dr[UW + 1];
            const float fx = s_fx[p], fy = s_fy[p];
            const float w00 = (1.f - fx) * (1.f - fy);
            const float w01 = fx * (1.f - fy);
            const float w10 = (1.f - fx) * fy;
            const float w11 = fx * fy;
            const float r = (w00 * d00 + w01 * d01 + w10 * d10 + w11 * d11) * 0.0625f;
            const int n = n0 + ((p >> 3) << 6) + (p & 7);
            outc[(size_t)(b * KWIN + k) * HW + n] = r;
        }
    } else {
        // ---- fallback: general coords, per-pixel gather (block-uniform) ----
        float* sDw = (float*)RAW + wv * 64;
        for (int p = wv; p < 32; p += 8) {
            const int n = n0 + ((p >> 3) << 6) + (p & 7);
            const float cx = c0[(b * 2 + 0) * HW + n];
            const float cy = c0[(b * 2 + 1) * HW + n];
            const float x0f = floorf(cx), y0f = floorf(cy);
            const float fx = cx - x0f, fy = cy - y0f;
            const int bx = (int)x0f - 3, by = (int)y0f - 3;
            const int ix = l & 7, iy = l >> 3;
            const int px = bx + ix, py = by + iy;
            float a = 0.f;
            if (px >= 0 && px < WDIM && py >= 0 && py < WDIM) {
                const ushort* qr = f1u + (size_t)n * CCH;
                const ushort* wr = f2u + (size_t)(py * WDIM + px) * CCH;
                for (int c = 0; c < 32; ++c) {
                    const uint4 uq = *(const uint4*)(qr + c * 8);
                    const uint4 uw = *(const uint4*)(wr + c * 8);
                    float2 m;
                    m = __half22float2(__hmul2(u2h2(uq.x), u2h2(uw.x))); a += m.x + m.y;
                    m = __half22float2(__hmul2(u2h2(uq.y), u2h2(uw.y))); a += m.x + m.y;
                    m = __half22float2(__hmul2(u2h2(uq.z), u2h2(uw.z))); a += m.x + m.y;
                    m = __half22float2(__hmul2(u2h2(uq.w), u2h2(uw.w))); a += m.x + m.y;
                }
            }
            sDw[l] = a;   // same-wave producer/consumer
            const int k = l;
            if (k < KWIN) {
                const int dyi = k / 7, dxi = k - dyi * 7;
                const int s = dyi * 8 + dxi;
                const float d00 = sDw[s], d01 = sDw[s + 1];
                const float d10 = sDw[s + 8], d11 = sDw[s + 9];
                const float w00 = (1.f - fx) * (1.f - fy);
                const float w01 = fx * (1.f - fy);
                const float w10 = (1.f - fx) * fy;
                const float w11 = fx * fy;
                const float r = (w00 * d00 + w01 * d01 + w10 * d10 + w11 * d11) * 0.0625f;
                outc[(size_t)(b * KWIN + k) * HW + n] = r;
            }
        }
    }
}

extern "C" void kernel_launch(void* const* d_in, const int* in_sizes, int n_in,
                              void* d_out, int out_size, void* d_ws, size_t ws_size,
                              hipStream_t stream) {
    (void)in_sizes; (void)n_in; (void)out_size; (void)ws_size;
    const float* f1 = (const float*)d_in[0];
    const float* f2 = (const float*)d_in[1];
    const float* c1 = (const float*)d_in[2];
    const float* c0 = (const float*)d_in[3];
    float* out = (float*)d_out;

    __half* f1t  = (__half*)d_ws;                     // [B,HW,C] f16, 4 MB
    __half* f2wt = f1t + (size_t)BATCH * HW * CCH;    // [B,HW,C] f16, 4 MB

    dim3 g1(BATCH * (HW / 64), CCH / 64);
    warp_transpose_kernel<<<g1, 256, 0, stream>>>(f1, f2, c1, f1t, f2wt, out);

    corr_mfma_kernel<<<(BATCH * HW) / 32, 512, 0, stream>>>(f1t, f2wt, c0, out + BATCH * 2 * HW);
}

// Round 6
// 25.731 us; speedup vs baseline: 1.2778x; 1.0489x over previous
//
#include <hip/hip_runtime.h>
#include <hip/hip_fp16.h>

#define BATCH 2
#define CCH   256
#define WDIM  64
#define HW    4096   // 64*64
#define KWIN  49

// corr tile geometry: 8 wide (x) x 4 tall (y) = 32 pixels per block
#define UW    15     // union window cols  (8 px x-span + 7)
#define UH    11     // union window rows  (4 px y-span + 7)
#define UPOS  165    // UW*UH
#define DSTR  177    // D row stride (odd -> bank spread)
#define BITEMS (UPOS * 16)   // 2640 uint4 items per B half
#define NSLOT 6              // ceil(2640 / 512)

using f16x8 = __attribute__((ext_vector_type(8))) _Float16;
using f32x4 = __attribute__((ext_vector_type(4))) float;

__device__ __forceinline__ __half2 u2h2(unsigned u) {
    union { unsigned u; __half2 h; } v; v.u = u; return v.h;
}
__device__ __forceinline__ unsigned h22u(__half2 h) {
    union { unsigned u; __half2 h; } v; v.h = h; return v.u;
}
__device__ __forceinline__ f16x8 ldfrag(const ushort* p) {
    return __builtin_bit_cast(f16x8, *(const uint4*)p);
}

// ---------------------------------------------------------------------------
// Kernel 1: bilinear warp of f2 by c1 (zero padding) fused with transpose of
// f2w AND f1 into channel-last f16 [B, HW, C], plus c1 passthrough (out 0).
// 32 channels per block: grid = (128, 8), block = 256 -> 4 blocks/CU,
// 16 waves/CU for latency hiding (was 2 blocks/CU at 64ch).
// LDS 2 x [32][65] padded fp32 tiles (16.6 KB).
// ---------------------------------------------------------------------------
__global__ __launch_bounds__(256) void warp_transpose_kernel(
    const float* __restrict__ f1, const float* __restrict__ f2,
    const float* __restrict__ c1, __half* __restrict__ f1t,
    __half* __restrict__ f2wt, float* __restrict__ out0)
{
    __shared__ float s1[32][65];
    __shared__ float s2[32][65];

    const int t  = threadIdx.x;
    const int b  = blockIdx.x >> 6;
    const int nb = (blockIdx.x & 63) << 6;
    const int cc = blockIdx.y << 5;          // 32-channel slice

    if (blockIdx.y == 0 && t < 128) {
        const int idx = blockIdx.x * 128 + t;
        out0[idx] = c1[idx];
    }

    const int pix = t & 63;
    const int tq  = t >> 6;
    const int n   = nb + pix;

    const float cx = c1[(b * 2 + 0) * HW + n];
    const float cy = c1[(b * 2 + 1) * HW + n];
    const float x0f = floorf(cx), y0f = floorf(cy);
    const float fx = cx - x0f, fy = cy - y0f;
    const int ix0 = (int)x0f, iy0 = (int)y0f;
    const int ix1 = ix0 + 1,  iy1 = iy0 + 1;

    float w00 = (1.f - fx) * (1.f - fy);
    float w01 = fx * (1.f - fy);
    float w10 = (1.f - fx) * fy;
    float w11 = fx * fy;
    if (ix0 < 0 || ix0 >= WDIM) { w00 = 0.f; w10 = 0.f; }
    if (ix1 < 0 || ix1 >= WDIM) { w01 = 0.f; w11 = 0.f; }
    if (iy0 < 0 || iy0 >= WDIM) { w00 = 0.f; w01 = 0.f; }
    if (iy1 < 0 || iy1 >= WDIM) { w10 = 0.f; w11 = 0.f; }
    const int xc0 = min(max(ix0, 0), WDIM - 1);
    const int xc1 = min(max(ix1, 0), WDIM - 1);
    const int yc0 = min(max(iy0, 0), WDIM - 1);
    const int yc1 = min(max(iy1, 0), WDIM - 1);
    const int o00 = yc0 * WDIM + xc0, o01 = yc0 * WDIM + xc1;
    const int o10 = yc1 * WDIM + xc0, o11 = yc1 * WDIM + xc1;

    const float* f2b = f2 + ((size_t)b * CCH + cc) * HW;
    const float* f1b = f1 + ((size_t)b * CCH + cc) * HW;

    #pragma unroll
    for (int j = 0; j < 8; ++j) {
        const int cl = tq * 8 + j;               // local channel 0..31
        const float* p2 = f2b + (size_t)cl * HW;
        s2[cl][pix] = w00 * p2[o00] + w01 * p2[o01] +
                      w10 * p2[o10] + w11 * p2[o11];
        s1[cl][pix] = f1b[(size_t)cl * HW + n];
    }
    __syncthreads();

    // phase B: lane packs 4 consecutive channels of one pixel -> uint2 store
    const int lo = t & 7;                        // channel quad 0..7
    const int pq = t >> 3;                       // pixel 0..31
    ushort* o1 = (ushort*)f1t;
    ushort* o2 = (ushort*)f2wt;
    #pragma unroll
    for (int j = 0; j < 2; ++j) {
        const int pix2 = j * 32 + pq;
        const int c4 = 4 * lo;
        const size_t base = ((size_t)(b * HW + nb + pix2)) * CCH + cc + c4;
        uint2 va, vb;
        va.x = h22u(__float22half2_rn(make_float2(s1[c4 + 0][pix2], s1[c4 + 1][pix2])));
        va.y = h22u(__float22half2_rn(make_float2(s1[c4 + 2][pix2], s1[c4 + 3][pix2])));
        vb.x = h22u(__float22half2_rn(make_float2(s2[c4 + 0][pix2], s2[c4 + 1][pix2])));
        vb.y = h22u(__float22half2_rn(make_float2(s2[c4 + 2][pix2], s2[c4 + 3][pix2])));
        *(uint2*)(o1 + base) = va;
        *(uint2*)(o2 + base) = vb;
    }
}

// ---------------------------------------------------------------------------
// Kernel 2: tiled MFMA correlation, pipelined.
// Block = 4x8 pixel tile (32 px), 512 thr (8 waves), grid 256 (XCD-swizzled).
// Restructure vs R5: (a) span-reduce computed redundantly by every wave
// in-register (no meta barrier; A loads issue first and overlap it);
// (b) T14 async-STAGE: both B-half global loads issued up front into regs,
// half-1 ds_write happens after the half-0 MFMA barrier (latency hidden).
// ---------------------------------------------------------------------------
__global__ __launch_bounds__(512) void corr_mfma_kernel(
    const __half* __restrict__ f1t, const __half* __restrict__ f2wt,
    const float* __restrict__ c0, float* __restrict__ outc)
{
    // RAW: A16 [32 rows][32 chunks][16B] = 16 KB, B16 [176 rows][16 chunks][16B] = 44 KB
    __shared__ __align__(16) char RAW[16384 + 176 * 128 * 2];
    __shared__ float s_fx[32], s_fy[32];
    __shared__ int   s_lbx[32], s_lby[32];

    ushort* A16 = (ushort*)RAW;
    ushort* B16 = (ushort*)(RAW + 16384);
    float*  Dex = (float*)(RAW + 16384);      // overlays B after compute

    const int t    = threadIdx.x;
    const int l    = t & 63;
    const int wv   = t >> 6;

    // XCD-aware bijective swizzle: 256 = 8 * 32
    const int bid = blockIdx.x;
    const int swz = (bid & 7) * 32 + (bid >> 3);
    const int b   = swz >> 7;
    const int tau = swz & 127;
    const int ty  = tau >> 3, tx = tau & 7;
    const int n0  = ty * 256 + tx * 8;        // tile base pixel

    const ushort* f1u = (const ushort*)f1t + ((size_t)b * HW) * CCH;
    const ushort* f2u = (const ushort*)f2wt + ((size_t)b * HW) * CCH;

    // ---- issue A loads first (independent of meta) ----
    const int ar0 = t >> 4,  ac0 = t & 15;          // item t    : r=t>>5? no:
    // A items: 1024 = 32 rows x 32 chunks; thread handles t and t+512
    const int r0 = t >> 5,        c0i = t & 31;
    const int r1 = (t + 512) >> 5, c1i = (t + 512) & 31;
    const int an0 = n0 + ((r0 >> 3) << 6) + (r0 & 7);
    const int an1 = n0 + ((r1 >> 3) << 6) + (r1 & 7);
    const uint4 av0 = *(const uint4*)(f1u + (size_t)an0 * CCH + c0i * 8);
    const uint4 av1 = *(const uint4*)(f1u + (size_t)an1 * CCH + c1i * 8);
    (void)ar0; (void)ac0;

    // ---- meta: every wave computes the span reduce redundantly ----
    float pcx = 0.f, pcy = 0.f;
    int ifx = 0, ify = 0;
    {
        const int p = l;
        if (p < 32) {
            const int n = n0 + ((p >> 3) << 6) + (p & 7);
            pcx = c0[(b * 2 + 0) * HW + n];
            pcy = c0[(b * 2 + 1) * HW + n];
            ifx = (int)floorf(pcx);
            ify = (int)floorf(pcy);
        }
    }
    int mnx = (l < 32) ? ifx : 0x7fffffff;
    int mxx = (l < 32) ? ifx : (-0x7fffffff - 1);
    int mny = (l < 32) ? ify : 0x7fffffff;
    int mxy = (l < 32) ? ify : (-0x7fffffff - 1);
    #pragma unroll
    for (int off = 1; off < 64; off <<= 1) {
        mnx = min(mnx, __shfl_xor(mnx, off, 64));
        mxx = max(mxx, __shfl_xor(mxx, off, 64));
        mny = min(mny, __shfl_xor(mny, off, 64));
        mxy = max(mxy, __shfl_xor(mxy, off, 64));
    }
    const int bx0 = mnx - 3, by0 = mny - 3;
    const int contained = (mxx - mnx <= 7) && (mxy - mny <= 3);

    if (wv == 0 && l < 32) {
        s_fx[l]  = pcx - floorf(pcx);
        s_fy[l]  = pcy - floorf(pcy);
        s_lbx[l] = ifx - mnx;
        s_lby[l] = ify - mny;
    }

    if (contained) {
        // ---- issue BOTH B-half loads into registers (T14 split) ----
        uint4 b0[NSLOT], b1[NSLOT];
        int   bofs[NSLOT];
        #pragma unroll
        for (int k = 0; k < NSLOT; ++k) {
            const int idx = t + k * 512;
            bofs[k] = -1;
            b0[k] = uint4{0u, 0u, 0u, 0u};
            b1[k] = uint4{0u, 0u, 0u, 0u};
            if (idx < BITEMS) {
                const int r = idx >> 4, c = idx & 15;
                const int wy = r / UW, wx = r - wy * UW;
                const int py = by0 + wy, px = bx0 + wx;
                bofs[k] = r * 128 + ((c ^ (r & 7)) << 3);
                if (px >= 0 && px < WDIM && py >= 0 && py < WDIM) {
                    const ushort* src = f2u + (size_t)(py * WDIM + px) * CCH + c * 8;
                    b0[k] = *(const uint4*)(src);
                    b1[k] = *(const uint4*)(src + 128);
                }
            }
        }

        // ---- ds_write A + B half 0 ----
        *(uint4*)(A16 + r0 * 256 + ((c0i ^ (r0 & 7)) << 3)) = av0;
        *(uint4*)(A16 + r1 * 256 + ((c1i ^ (r1 & 7)) << 3)) = av1;
        #pragma unroll
        for (int k = 0; k < NSLOT; ++k)
            if (bofs[k] >= 0) *(uint4*)(B16 + bofs[k]) = b0[k];
        __syncthreads();

        // ---- MFMA setup ----
        const int mt = wv & 1;          // m-tile (16 px)
        const int ng = wv >> 1;         // n-group
        const int nnt = (ng == 3) ? 2 : 3;
        int nt[3] = {ng, ng + 4, ng + 8};
        f32x4 acc[3];
        #pragma unroll
        for (int i = 0; i < 3; ++i) acc[i] = f32x4{0.f, 0.f, 0.f, 0.f};

        const int g    = l >> 4;
        const int arow = mt * 16 + (l & 15);
        const int axr  = arow & 7;

        // half 0
        {
            f16x8 af[4];
            #pragma unroll
            for (int s = 0; s < 4; ++s)
                af[s] = ldfrag(A16 + arow * 256 + (((s * 4 + g) ^ axr) << 3));
            #pragma unroll
            for (int i = 0; i < 3; ++i) if (i < nnt) {
                const int brow = nt[i] * 16 + (l & 15);
                const int bxr  = brow & 7;
                #pragma unroll
                for (int s = 0; s < 4; ++s) {
                    const f16x8 bf = ldfrag(B16 + brow * 128 + (((s * 4 + g) ^ bxr) << 3));
                    acc[i] = __builtin_amdgcn_mfma_f32_16x16x32_f16(af[s], bf, acc[i], 0, 0, 0);
                }
            }
        }
        __syncthreads();   // all B-half-0 reads done

        // ---- ds_write B half 1 (loads returned during half-0 MFMA) ----
        #pragma unroll
        for (int k = 0; k < NSLOT; ++k)
            if (bofs[k] >= 0) *(uint4*)(B16 + bofs[k]) = b1[k];
        __syncthreads();

        // half 1
        {
            f16x8 af[4];
            #pragma unroll
            for (int s = 0; s < 4; ++s)
                af[s] = ldfrag(A16 + arow * 256 + (((16 + s * 4 + g) ^ axr) << 3));
            #pragma unroll
            for (int i = 0; i < 3; ++i) if (i < nnt) {
                const int brow = nt[i] * 16 + (l & 15);
                const int bxr  = brow & 7;
                #pragma unroll
                for (int s = 0; s < 4; ++s) {
                    const f16x8 bf = ldfrag(B16 + brow * 128 + (((s * 4 + g) ^ bxr) << 3));
                    acc[i] = __builtin_amdgcn_mfma_f32_16x16x32_f16(af[s], bf, acc[i], 0, 0, 0);
                }
            }
        }
        __syncthreads();   // A,B dead -> D may overlay

        // ---- D -> LDS ----
        #pragma unroll
        for (int i = 0; i < 3; ++i) if (i < nnt) {
            #pragma unroll
            for (int r4 = 0; r4 < 4; ++r4) {
                Dex[(mt * 16 + (l >> 4) * 4 + r4) * DSTR + nt[i] * 16 + (l & 15)] = acc[i][r4];
            }
        }
        __syncthreads();

        // ---- output: bilinear combine of 4 D entries per (pixel, k) ----
        for (int idx = t; idx < 32 * KWIN; idx += 512) {
            const int p = idx & 31, k = idx >> 5;
            const int dyi = k / 7, dxi = k - dyi * 7;
            const int pos = (s_lby[p] + dyi) * UW + s_lbx[p] + dxi;
            const float* dr = Dex + p * DSTR + pos;
            const float d00 = dr[0], d01 = dr[1], d10 = dr[UW], d11 = dr[UW + 1];
            const float fx = s_fx[p], fy = s_fy[p];
            const float w00 = (1.f - fx) * (1.f - fy);
            const float w01 = fx * (1.f - fy);
            const float w10 = (1.f - fx) * fy;
            const float w11 = fx * fy;
            const float r = (w00 * d00 + w01 * d01 + w10 * d10 + w11 * d11) * 0.0625f;
            const int n = n0 + ((p >> 3) << 6) + (p & 7);
            outc[(size_t)(b * KWIN + k) * HW + n] = r;
        }
    } else {
        // ---- fallback: general coords, per-pixel gather (block-uniform) ----
        float* sDw = (float*)RAW + wv * 64;
        for (int p = wv; p < 32; p += 8) {
            const int n = n0 + ((p >> 3) << 6) + (p & 7);
            const float cx = c0[(b * 2 + 0) * HW + n];
            const float cy = c0[(b * 2 + 1) * HW + n];
            const float x0f = floorf(cx), y0f = floorf(cy);
            const float fx = cx - x0f, fy = cy - y0f;
            const int bx = (int)x0f - 3, by = (int)y0f - 3;
            const int ix = l & 7, iy = l >> 3;
            const int px = bx + ix, py = by + iy;
            float a = 0.f;
            if (px >= 0 && px < WDIM && py >= 0 && py < WDIM) {
                const ushort* qr = f1u + (size_t)n * CCH;
                const ushort* wr = f2u + (size_t)(py * WDIM + px) * CCH;
                for (int c = 0; c < 32; ++c) {
                    const uint4 uq = *(const uint4*)(qr + c * 8);
                    const uint4 uw = *(const uint4*)(wr + c * 8);
                    float2 m;
                    m = __half22float2(__hmul2(u2h2(uq.x), u2h2(uw.x))); a += m.x + m.y;
                    m = __half22float2(__hmul2(u2h2(uq.y), u2h2(uw.y))); a += m.x + m.y;
                    m = __half22float2(__hmul2(u2h2(uq.z), u2h2(uw.z))); a += m.x + m.y;
                    m = __half22float2(__hmul2(u2h2(uq.w), u2h2(uw.w))); a += m.x + m.y;
                }
            }
            sDw[l] = a;   // same-wave producer/consumer
            const int k = l;
            if (k < KWIN) {
                const int dyi = k / 7, dxi = k - dyi * 7;
                const int s = dyi * 8 + dxi;
                const float d00 = sDw[s], d01 = sDw[s + 1];
                const float d10 = sDw[s + 8], d11 = sDw[s + 9];
                const float w00 = (1.f - fx) * (1.f - fy);
                const float w01 = fx * (1.f - fy);
                const float w10 = (1.f - fx) * fy;
                const float w11 = fx * fy;
                const float r = (w00 * d00 + w01 * d01 + w10 * d10 + w11 * d11) * 0.0625f;
                outc[(size_t)(b * KWIN + k) * HW + n] = r;
            }
        }
    }
}

extern "C" void kernel_launch(void* const* d_in, const int* in_sizes, int n_in,
                              void* d_out, int out_size, void* d_ws, size_t ws_size,
                              hipStream_t stream) {
    (void)in_sizes; (void)n_in; (void)out_size; (void)ws_size;
    const float* f1 = (const float*)d_in[0];
    const float* f2 = (const float*)d_in[1];
    const float* c1 = (const float*)d_in[2];
    const float* c0 = (const float*)d_in[3];
    float* out = (float*)d_out;

    __half* f1t  = (__half*)d_ws;                     // [B,HW,C] f16, 4 MB
    __half* f2wt = f1t + (size_t)BATCH * HW * CCH;    // [B,HW,C] f16, 4 MB

    dim3 g1(BATCH * (HW / 64), CCH / 32);
    warp_transpose_kernel<<<g1, 256, 0, stream>>>(f1, f2, c1, f1t, f2wt, out);

    corr_mfma_kernel<<<(BATCH * HW) / 32, 512, 0, stream>>>(f1t, f2wt, c0, out + BATCH * 2 * HW);
}

// Round 7
// 21.819 us; speedup vs baseline: 1.5069x; 1.1793x over previous
//
#include <hip/hip_runtime.h>
#include <hip/hip_fp16.h>

#define BATCH 2
#define CCH   256
#define WDIM  64
#define HW    4096   // 64*64
#define KWIN  49

// corr tile geometry: 8 wide (x) x 4 tall (y) = 32 pixels per block
#define UW    15     // union window cols  (8 px x-span + 7)
#define UH    11     // union window rows  (4 px y-span + 7)
#define UPOS  165    // UW*UH
#define DSTR  177    // D row stride (odd -> bank spread)
#define BITEMS (UPOS * 16)   // 2640 uint4 items per B half
#define NSLOT 6              // ceil(2640 / 512)

using f16x8 = __attribute__((ext_vector_type(8))) _Float16;
using f32x4 = __attribute__((ext_vector_type(4))) float;

__device__ __forceinline__ __half2 u2h2(unsigned u) {
    union { unsigned u; __half2 h; } v; v.u = u; return v.h;
}
__device__ __forceinline__ unsigned h22u(__half2 h) {
    union { unsigned u; __half2 h; } v; v.h = h; return v.u;
}
__device__ __forceinline__ f16x8 ldfrag(const ushort* p) {
    return __builtin_bit_cast(f16x8, *(const uint4*)p);
}

// ---------------------------------------------------------------------------
// Kernel T: pure coalesced transpose of f1 AND f2 into channel-last f16
// [B, HW, C] (f1t, f2t) + c1 passthrough (out 0). No gathers.
// grid = (128, 8), block = 256; LDS 2 x [32][65] fp32 tiles.
// ---------------------------------------------------------------------------
__global__ __launch_bounds__(256) void transpose_kernel(
    const float* __restrict__ f1, const float* __restrict__ f2,
    const float* __restrict__ c1, __half* __restrict__ f1t,
    __half* __restrict__ f2t, float* __restrict__ out0)
{
    __shared__ float s1[32][65];
    __shared__ float s2[32][65];

    const int t  = threadIdx.x;
    const int b  = blockIdx.x >> 6;
    const int nb = (blockIdx.x & 63) << 6;
    const int cc = blockIdx.y << 5;          // 32-channel slice

    if (blockIdx.y == 0 && t < 128) {
        const int idx = blockIdx.x * 128 + t;
        out0[idx] = c1[idx];
    }

    const int pix = t & 63;
    const int tq  = t >> 6;
    const int n   = nb + pix;

    const float* f2b = f2 + ((size_t)b * CCH + cc) * HW;
    const float* f1b = f1 + ((size_t)b * CCH + cc) * HW;

    #pragma unroll
    for (int j = 0; j < 8; ++j) {
        const int cl = tq * 8 + j;               // local channel 0..31
        s2[cl][pix] = f2b[(size_t)cl * HW + n];
        s1[cl][pix] = f1b[(size_t)cl * HW + n];
    }
    __syncthreads();

    // phase B: lane packs 4 consecutive channels of one pixel -> uint2 store
    const int lo = t & 7;                        // channel quad 0..7
    const int pq = t >> 3;                       // pixel 0..31
    ushort* o1 = (ushort*)f1t;
    ushort* o2 = (ushort*)f2t;
    #pragma unroll
    for (int j = 0; j < 2; ++j) {
        const int pix2 = j * 32 + pq;
        const int c4 = 4 * lo;
        const size_t base = ((size_t)(b * HW + nb + pix2)) * CCH + cc + c4;
        uint2 va, vb;
        va.x = h22u(__float22half2_rn(make_float2(s1[c4 + 0][pix2], s1[c4 + 1][pix2])));
        va.y = h22u(__float22half2_rn(make_float2(s1[c4 + 2][pix2], s1[c4 + 3][pix2])));
        vb.x = h22u(__float22half2_rn(make_float2(s2[c4 + 0][pix2], s2[c4 + 1][pix2])));
        vb.y = h22u(__float22half2_rn(make_float2(s2[c4 + 2][pix2], s2[c4 + 3][pix2])));
        *(uint2*)(o1 + base) = va;
        *(uint2*)(o2 + base) = vb;
    }
}

// ---------------------------------------------------------------------------
// Kernel W: bilinear warp in channel-last space. Per pixel, the 4 corner
// feature vectors are contiguous 512B runs of f2t -> each corner-load
// instruction touches 8 cache lines (vs ~40 in channel-major gather).
// fp32 combine, single f16 rounding at store. Thread = (pixel, 16B chunk):
// block 256 thr = 8 px x 32 chunks; grid = B*HW/8 = 1024.
// ---------------------------------------------------------------------------
__global__ __launch_bounds__(256) void warp_cl_kernel(
    const __half* __restrict__ f2t, const float* __restrict__ c1,
    __half* __restrict__ f2wt)
{
    const int t     = threadIdx.x;
    const int chunk = t & 31;     // uint4 chunk within 256 ch
    const int pl    = t >> 5;     // pixel 0..7
    const int ng    = blockIdx.x * 8 + pl;
    const int b     = ng >> 12;
    const int n     = ng & 4095;

    const float cx = c1[(b * 2 + 0) * HW + n];
    const float cy = c1[(b * 2 + 1) * HW + n];
    const float x0f = floorf(cx), y0f = floorf(cy);
    const float fx = cx - x0f, fy = cy - y0f;
    const int ix0 = (int)x0f, iy0 = (int)y0f;
    const int ix1 = ix0 + 1,  iy1 = iy0 + 1;

    float w00 = (1.f - fx) * (1.f - fy);
    float w01 = fx * (1.f - fy);
    float w10 = (1.f - fx) * fy;
    float w11 = fx * fy;
    if (ix0 < 0 || ix0 >= WDIM) { w00 = 0.f; w10 = 0.f; }
    if (ix1 < 0 || ix1 >= WDIM) { w01 = 0.f; w11 = 0.f; }
    if (iy0 < 0 || iy0 >= WDIM) { w00 = 0.f; w01 = 0.f; }
    if (iy1 < 0 || iy1 >= WDIM) { w10 = 0.f; w11 = 0.f; }
    const int xc0 = min(max(ix0, 0), WDIM - 1);
    const int xc1 = min(max(ix1, 0), WDIM - 1);
    const int yc0 = min(max(iy0, 0), WDIM - 1);
    const int yc1 = min(max(iy1, 0), WDIM - 1);

    const ushort* base = (const ushort*)f2t + ((size_t)b * HW) * CCH + chunk * 8;
    const uint4 v00 = *(const uint4*)(base + (size_t)(yc0 * WDIM + xc0) * CCH);
    const uint4 v01 = *(const uint4*)(base + (size_t)(yc0 * WDIM + xc1) * CCH);
    const uint4 v10 = *(const uint4*)(base + (size_t)(yc1 * WDIM + xc0) * CCH);
    const uint4 v11 = *(const uint4*)(base + (size_t)(yc1 * WDIM + xc1) * CCH);

    float acc[8] = {0.f, 0.f, 0.f, 0.f, 0.f, 0.f, 0.f, 0.f};
    auto addc = [&](uint4 u, float w) {
        float2 m;
        m = __half22float2(u2h2(u.x)); acc[0] += w * m.x; acc[1] += w * m.y;
        m = __half22float2(u2h2(u.y)); acc[2] += w * m.x; acc[3] += w * m.y;
        m = __half22float2(u2h2(u.z)); acc[4] += w * m.x; acc[5] += w * m.y;
        m = __half22float2(u2h2(u.w)); acc[6] += w * m.x; acc[7] += w * m.y;
    };
    addc(v00, w00); addc(v01, w01); addc(v10, w10); addc(v11, w11);

    uint4 o;
    o.x = h22u(__float22half2_rn(make_float2(acc[0], acc[1])));
    o.y = h22u(__float22half2_rn(make_float2(acc[2], acc[3])));
    o.z = h22u(__float22half2_rn(make_float2(acc[4], acc[5])));
    o.w = h22u(__float22half2_rn(make_float2(acc[6], acc[7])));
    *(uint4*)((ushort*)f2wt + ((size_t)(b * HW + n)) * CCH + chunk * 8) = o;
}

// ---------------------------------------------------------------------------
// Kernel 2 (unchanged from R6): tiled MFMA correlation, pipelined.
// ---------------------------------------------------------------------------
__global__ __launch_bounds__(512) void corr_mfma_kernel(
    const __half* __restrict__ f1t, const __half* __restrict__ f2wt,
    const float* __restrict__ c0, float* __restrict__ outc)
{
    __shared__ __align__(16) char RAW[16384 + 176 * 128 * 2];
    __shared__ float s_fx[32], s_fy[32];
    __shared__ int   s_lbx[32], s_lby[32];

    ushort* A16 = (ushort*)RAW;
    ushort* B16 = (ushort*)(RAW + 16384);
    float*  Dex = (float*)(RAW + 16384);      // overlays B after compute

    const int t    = threadIdx.x;
    const int l    = t & 63;
    const int wv   = t >> 6;

    // XCD-aware bijective swizzle: 256 = 8 * 32
    const int bid = blockIdx.x;
    const int swz = (bid & 7) * 32 + (bid >> 3);
    const int b   = swz >> 7;
    const int tau = swz & 127;
    const int ty  = tau >> 3, tx = tau & 7;
    const int n0  = ty * 256 + tx * 8;        // tile base pixel

    const ushort* f1u = (const ushort*)f1t + ((size_t)b * HW) * CCH;
    const ushort* f2u = (const ushort*)f2wt + ((size_t)b * HW) * CCH;

    // ---- issue A loads first (independent of meta) ----
    const int r0 = t >> 5,         c0i = t & 31;
    const int r1 = (t + 512) >> 5, c1i = (t + 512) & 31;
    const int an0 = n0 + ((r0 >> 3) << 6) + (r0 & 7);
    const int an1 = n0 + ((r1 >> 3) << 6) + (r1 & 7);
    const uint4 av0 = *(const uint4*)(f1u + (size_t)an0 * CCH + c0i * 8);
    const uint4 av1 = *(const uint4*)(f1u + (size_t)an1 * CCH + c1i * 8);

    // ---- meta: every wave computes the span reduce redundantly ----
    float pcx = 0.f, pcy = 0.f;
    int ifx = 0, ify = 0;
    if (l < 32) {
        const int n = n0 + ((l >> 3) << 6) + (l & 7);
        pcx = c0[(b * 2 + 0) * HW + n];
        pcy = c0[(b * 2 + 1) * HW + n];
        ifx = (int)floorf(pcx);
        ify = (int)floorf(pcy);
    }
    int mnx = (l < 32) ? ifx : 0x7fffffff;
    int mxx = (l < 32) ? ifx : (-0x7fffffff - 1);
    int mny = (l < 32) ? ify : 0x7fffffff;
    int mxy = (l < 32) ? ify : (-0x7fffffff - 1);
    #pragma unroll
    for (int off = 1; off < 64; off <<= 1) {
        mnx = min(mnx, __shfl_xor(mnx, off, 64));
        mxx = max(mxx, __shfl_xor(mxx, off, 64));
        mny = min(mny, __shfl_xor(mny, off, 64));
        mxy = max(mxy, __shfl_xor(mxy, off, 64));
    }
    const int bx0 = mnx - 3, by0 = mny - 3;
    const int contained = (mxx - mnx <= 7) && (mxy - mny <= 3);

    if (wv == 0 && l < 32) {
        s_fx[l]  = pcx - floorf(pcx);
        s_fy[l]  = pcy - floorf(pcy);
        s_lbx[l] = ifx - mnx;
        s_lby[l] = ify - mny;
    }

    if (contained) {
        // ---- issue BOTH B-half loads into registers (T14 split) ----
        uint4 b0[NSLOT], b1[NSLOT];
        int   bofs[NSLOT];
        #pragma unroll
        for (int k = 0; k < NSLOT; ++k) {
            const int idx = t + k * 512;
            bofs[k] = -1;
            b0[k] = uint4{0u, 0u, 0u, 0u};
            b1[k] = uint4{0u, 0u, 0u, 0u};
            if (idx < BITEMS) {
                const int r = idx >> 4, c = idx & 15;
                const int wy = r / UW, wx = r - wy * UW;
                const int py = by0 + wy, px = bx0 + wx;
                bofs[k] = r * 128 + ((c ^ (r & 7)) << 3);
                if (px >= 0 && px < WDIM && py >= 0 && py < WDIM) {
                    const ushort* src = f2u + (size_t)(py * WDIM + px) * CCH + c * 8;
                    b0[k] = *(const uint4*)(src);
                    b1[k] = *(const uint4*)(src + 128);
                }
            }
        }

        // ---- ds_write A + B half 0 ----
        *(uint4*)(A16 + r0 * 256 + ((c0i ^ (r0 & 7)) << 3)) = av0;
        *(uint4*)(A16 + r1 * 256 + ((c1i ^ (r1 & 7)) << 3)) = av1;
        #pragma unroll
        for (int k = 0; k < NSLOT; ++k)
            if (bofs[k] >= 0) *(uint4*)(B16 + bofs[k]) = b0[k];
        __syncthreads();

        // ---- MFMA setup ----
        const int mt = wv & 1;          // m-tile (16 px)
        const int ng = wv >> 1;         // n-group
        const int nnt = (ng == 3) ? 2 : 3;
        int nt[3] = {ng, ng + 4, ng + 8};
        f32x4 acc[3];
        #pragma unroll
        for (int i = 0; i < 3; ++i) acc[i] = f32x4{0.f, 0.f, 0.f, 0.f};

        const int g    = l >> 4;
        const int arow = mt * 16 + (l & 15);
        const int axr  = arow & 7;

        // half 0
        {
            f16x8 af[4];
            #pragma unroll
            for (int s = 0; s < 4; ++s)
                af[s] = ldfrag(A16 + arow * 256 + (((s * 4 + g) ^ axr) << 3));
            #pragma unroll
            for (int i = 0; i < 3; ++i) if (i < nnt) {
                const int brow = nt[i] * 16 + (l & 15);
                const int bxr  = brow & 7;
                #pragma unroll
                for (int s = 0; s < 4; ++s) {
                    const f16x8 bf = ldfrag(B16 + brow * 128 + (((s * 4 + g) ^ bxr) << 3));
                    acc[i] = __builtin_amdgcn_mfma_f32_16x16x32_f16(af[s], bf, acc[i], 0, 0, 0);
                }
            }
        }
        __syncthreads();   // all B-half-0 reads done

        // ---- ds_write B half 1 (loads returned during half-0 MFMA) ----
        #pragma unroll
        for (int k = 0; k < NSLOT; ++k)
            if (bofs[k] >= 0) *(uint4*)(B16 + bofs[k]) = b1[k];
        __syncthreads();

        // half 1
        {
            f16x8 af[4];
            #pragma unroll
            for (int s = 0; s < 4; ++s)
                af[s] = ldfrag(A16 + arow * 256 + (((16 + s * 4 + g) ^ axr) << 3));
            #pragma unroll
            for (int i = 0; i < 3; ++i) if (i < nnt) {
                const int brow = nt[i] * 16 + (l & 15);
                const int bxr  = brow & 7;
                #pragma unroll
                for (int s = 0; s < 4; ++s) {
                    const f16x8 bf = ldfrag(B16 + brow * 128 + (((s * 4 + g) ^ bxr) << 3));
                    acc[i] = __builtin_amdgcn_mfma_f32_16x16x32_f16(af[s], bf, acc[i], 0, 0, 0);
                }
            }
        }
        __syncthreads();   // A,B dead -> D may overlay

        // ---- D -> LDS ----
        #pragma unroll
        for (int i = 0; i < 3; ++i) if (i < nnt) {
            #pragma unroll
            for (int r4 = 0; r4 < 4; ++r4) {
                Dex[(mt * 16 + (l >> 4) * 4 + r4) * DSTR + nt[i] * 16 + (l & 15)] = acc[i][r4];
            }
        }
        __syncthreads();

        // ---- output: bilinear combine of 4 D entries per (pixel, k) ----
        for (int idx = t; idx < 32 * KWIN; idx += 512) {
            const int p = idx & 31, k = idx >> 5;
            const int dyi = k / 7, dxi = k - dyi * 7;
            const int pos = (s_lby[p] + dyi) * UW + s_lbx[p] + dxi;
            const float* dr = Dex + p * DSTR + pos;
            const float d00 = dr[0], d01 = dr[1], d10 = dr[UW], d11 = dr[UW + 1];
            const float fx = s_fx[p], fy = s_fy[p];
            const float w00 = (1.f - fx) * (1.f - fy);
            const float w01 = fx * (1.f - fy);
            const float w10 = (1.f - fx) * fy;
            const float w11 = fx * fy;
            const float r = (w00 * d00 + w01 * d01 + w10 * d10 + w11 * d11) * 0.0625f;
            const int n = n0 + ((p >> 3) << 6) + (p & 7);
            outc[(size_t)(b * KWIN + k) * HW + n] = r;
        }
    } else {
        // ---- fallback: general coords, per-pixel gather (block-uniform) ----
        float* sDw = (float*)RAW + wv * 64;
        for (int p = wv; p < 32; p += 8) {
            const int n = n0 + ((p >> 3) << 6) + (p & 7);
            const float cx = c0[(b * 2 + 0) * HW + n];
            const float cy = c0[(b * 2 + 1) * HW + n];
            const float x0f = floorf(cx), y0f = floorf(cy);
            const float fx = cx - x0f, fy = cy - y0f;
            const int bx = (int)x0f - 3, by = (int)y0f - 3;
            const int ix = l & 7, iy = l >> 3;
            const int px = bx + ix, py = by + iy;
            float a = 0.f;
            if (px >= 0 && px < WDIM && py >= 0 && py < WDIM) {
                const ushort* qr = f1u + (size_t)n * CCH;
                const ushort* wr = f2u + (size_t)(py * WDIM + px) * CCH;
                for (int c = 0; c < 32; ++c) {
                    const uint4 uq = *(const uint4*)(qr + c * 8);
                    const uint4 uw = *(const uint4*)(wr + c * 8);
                    float2 m;
                    m = __half22float2(__hmul2(u2h2(uq.x), u2h2(uw.x))); a += m.x + m.y;
                    m = __half22float2(__hmul2(u2h2(uq.y), u2h2(uw.y))); a += m.x + m.y;
                    m = __half22float2(__hmul2(u2h2(uq.z), u2h2(uw.z))); a += m.x + m.y;
                    m = __half22float2(__hmul2(u2h2(uq.w), u2h2(uw.w))); a += m.x + m.y;
                }
            }
            sDw[l] = a;   // same-wave producer/consumer
            const int k = l;
            if (k < KWIN) {
                const int dyi = k / 7, dxi = k - dyi * 7;
                const int s = dyi * 8 + dxi;
                const float d00 = sDw[s], d01 = sDw[s + 1];
                const float d10 = sDw[s + 8], d11 = sDw[s + 9];
                const float w00 = (1.f - fx) * (1.f - fy);
                const float w01 = fx * (1.f - fy);
                const float w10 = (1.f - fx) * fy;
                const float w11 = fx * fy;
                const float r = (w00 * d00 + w01 * d01 + w10 * d10 + w11 * d11) * 0.0625f;
                outc[(size_t)(b * KWIN + k) * HW + n] = r;
            }
        }
    }
}

extern "C" void kernel_launch(void* const* d_in, const int* in_sizes, int n_in,
                              void* d_out, int out_size, void* d_ws, size_t ws_size,
                              hipStream_t stream) {
    (void)in_sizes; (void)n_in; (void)out_size; (void)ws_size;
    const float* f1 = (const float*)d_in[0];
    const float* f2 = (const float*)d_in[1];
    const float* c1 = (const float*)d_in[2];
    const float* c0 = (const float*)d_in[3];
    float* out = (float*)d_out;

    const size_t PLANE = (size_t)BATCH * HW * CCH;   // 2M halfs = 4 MB
    __half* f1t  = (__half*)d_ws;          // [B,HW,C] f16
    __half* f2wt = f1t + PLANE;            // warped  [B,HW,C] f16
    __half* f2t  = f2wt + PLANE;           // plain   [B,HW,C] f16

    dim3 g1(BATCH * (HW / 64), CCH / 32);
    transpose_kernel<<<g1, 256, 0, stream>>>(f1, f2, c1, f1t, f2t, out);

    warp_cl_kernel<<<(BATCH * HW) / 8, 256, 0, stream>>>(f2t, c1, f2wt);

    corr_mfma_kernel<<<(BATCH * HW) / 32, 512, 0, stream>>>(f1t, f2wt, c0, out + BATCH * 2 * HW);
}